// Round 4
// baseline (3300.134 us; speedup 1.0000x reference)
//
#include <hip/hip_runtime.h>
#include <hip/hip_fp16.h>

#define L2E 1.4426950408889634f

// Problem dims
constexpr int Bb = 16, Ss = 128, Ii = 576, Uu = 512, Hh = 256;

// ws offsets (in 4-byte slots) — scan-phase layout
constexpr int OFF_A    = 0;        // 262144 f32  a  = sigma*log2e,      [j][i]
constexpr int OFF_C    = 262144;   // 262144 f32  c  = sigma*mu*log2e,   [j][i]
constexpr int OFF_WE   = 524288;   // 262144 f32  we = w*mask*erev,      [j][i]
constexpr int OFF_NUMS = 786432;   // 1048576 f32 sensory numerators (B*S, U)
constexpr int OFF_DENS = 1835008;  // 1048576 f32
constexpr int OFF_RING = 2883584;  // 65536 f32   [batch][8][512] v-exchange ring
constexpr int OFF_LTC  = 2949120;  // 524288 f32  ltc_out (B,S,H)
// post-scan overlays (params + NUMS/DENS dead after scan)
constexpr int OFF_Q    = 0;
constexpr int OFF_K    = 524288;
constexpr int OFF_V    = 1048576;
constexpr int OFF_MEM  = 1572864;
constexpr int OFF_HID  = 2097152;

constexpr unsigned SENT_U = 0x7FBADBADu;  // NaN-payload sentinel, unreachable by the LTC math

__device__ __forceinline__ float ex2(float x) { return __builtin_amdgcn_exp2f(x); }
__device__ __forceinline__ float rcpf(float x) { return __builtin_amdgcn_rcpf(x); }

// ---------------- param prep: f32 derived edge params, transposed to [j][i] ----------------
__global__ __launch_bounds__(256) void prep_kernel(
    const float* __restrict__ sigma, const float* __restrict__ mu,
    const float* __restrict__ w, const float* __restrict__ erev,
    const float* __restrict__ mask, float* __restrict__ ws)
{
    const int g = blockIdx.x * 256 + threadIdx.x;   // [0, 262144)
    // ring init: [batch][8][512]; slot 7 = h0 zeros, others sentinel
    if (g < 16 * 8 * 512) {
        const int r = (g >> 9) & 7;
        ws[OFF_RING + g] = (r == 7) ? 0.0f : __builtin_bit_cast(float, SENT_U);
    }
    const int jj = g & 511, i = g >> 9;             // coalesced source reads
    const int idx = i * 512 + jj;
    const float sg = sigma[idx], m = mu[idx];
    const float wm = w[idx] * mask[idx];
    const int tr = jj * 512 + i;                    // transposed (scatter) writes
    ws[OFF_A + tr]  = sg * L2E;
    ws[OFF_C + tr]  = sg * m * L2E;
    ws[OFF_WE + tr] = wm * erev[idx];
}

// ---------------- sensory precompute: w_num_s / w_den_s for all (b,t) ----------------
__global__ __launch_bounds__(256) void sensory_kernel(
    const float* __restrict__ x, const float* __restrict__ inw, const float* __restrict__ inb,
    const float* __restrict__ ssig, const float* __restrict__ smu,
    const float* __restrict__ sw, const float* __restrict__ serev,
    const float* __restrict__ smask, float* __restrict__ ws)
{
    __shared__ float inp[16 * 576];
    __shared__ float part[4096];               // [4][64][8][2]
    const int t = threadIdx.x;
    const int jb = blockIdx.x & 7, pb = blockIdx.x >> 3;
    #pragma unroll
    for (int e = 0; e < 9; ++e) {
        const int id = t + e * 256;            // [0,2304)
        const int off = id * 4;
        const int bs = off / 576, ii = off % 576;
        const float4 xv = *(const float4*)&x[(pb * 16 + bs) * 576 + ii];
        const float4 wv = *(const float4*)&inw[ii];
        const float4 bv = *(const float4*)&inb[ii];
        inp[off + 0] = fmaf(xv.x, wv.x, bv.x);
        inp[off + 1] = fmaf(xv.y, wv.y, bv.y);
        inp[off + 2] = fmaf(xv.z, wv.z, bv.z);
        inp[off + 3] = fmaf(xv.w, wv.w, bv.w);
    }
    __syncthreads();
    const int j = t & 63, c = t >> 6;
    const int jg = jb * 64 + j;
    float num[16], den[16];
    #pragma unroll
    for (int bs = 0; bs < 16; ++bs) { num[bs] = 0.f; den[bs] = 0.f; }
    for (int ii = c * 144; ii < (c + 1) * 144; ++ii) {
        const int pidx = ii * 512 + jg;
        const float sg = ssig[pidx], m = smu[pidx];
        const float wm = sw[pidx] * smask[pidx];
        const float we = wm * serev[pidx];
        const float a = sg * L2E, cc = sg * m * L2E;
        #pragma unroll
        for (int bs = 0; bs < 16; ++bs) {
            const float vv = inp[bs * 576 + ii];
            const float r = rcpf(1.f + ex2(fmaf(-a, vv, cc)));
            num[bs] = fmaf(we, r, num[bs]);
            den[bs] = fmaf(wm, r, den[bs]);
        }
    }
    #pragma unroll
    for (int pass = 0; pass < 2; ++pass) {
        __syncthreads();
        #pragma unroll
        for (int bs = 0; bs < 8; ++bs) {
            part[((c * 64 + j) * 8 + bs) * 2 + 0] = num[pass * 8 + bs];
            part[((c * 64 + j) * 8 + bs) * 2 + 1] = den[pass * 8 + bs];
        }
        __syncthreads();
        #pragma unroll
        for (int qd = 0; qd < 4; ++qd) {
            const int vid = t * 4 + qd;        // [0,1024)
            const int jj2 = vid >> 4, bs = (vid >> 1) & 7, which = vid & 1;
            const float acc =
                part[((0 * 64 + jj2) * 8 + bs) * 2 + which] + part[((1 * 64 + jj2) * 8 + bs) * 2 + which] +
                part[((2 * 64 + jj2) * 8 + bs) * 2 + which] + part[((3 * 64 + jj2) * 8 + bs) * 2 + which];
            const int p = pb * 16 + pass * 8 + bs;
            ws[(which ? OFF_DENS : OFF_NUMS) + p * 512 + jb * 64 + jj2] = acc;
        }
    }
}

// ---------------- persistent LTC scan v4: wave-autonomous, f32 reg params, no barriers ----------------
// 512 WGs = 16 batches x 32 slices. Wave owns 4 columns: lane = rg*4+colL, rg=rows rg*32..+31.
// Per phase per wave: poll 8 coalesced ring slots/lane -> stage into wave-PRIVATE swizzled LDS
// tile (zero bank conflicts, verified write+read) -> 32 edge evals (4 VALU + 2 trans each) ->
// 4x shfl_xor reduce -> owner lanes (0..3) update+store. No __syncthreads anywhere in the loop:
// intra-wave LDS ops are in-order; cross-WG sync is the sentinel ring (reset at distance 4;
// full-vector dependency enforces near-lockstep so the distance-4 reset is race-free).
__global__ __launch_bounds__(256, 2) void scan_kernel(
    const float* __restrict__ gleak, const float* __restrict__ vleak,
    const float* __restrict__ cmv,
    const float* __restrict__ outw, const float* __restrict__ outb,
    float* __restrict__ ws, float* __restrict__ dout)
{
    __shared__ float vlds[4][512];     // 8 KB, one private tile per wave

    const int t = threadIdx.x;
    const int wg = blockIdx.x;
    const int batch = wg & 15;
    const int slice = wg >> 4;
    const int wv = t >> 6;
    const int lane = t & 63;
    const int rg = lane >> 2;          // 0..15 -> rows rg*32..+31
    const int colL = lane & 3;
    const int j = slice * 16 + wv * 4 + colL;
    const bool owner = (lane < 4);     // rg == 0

    // one-time: f32 edge params into registers (96 VGPRs)
    float pa[32], pc[32], pwe[32];
    {
        const float4* Ag = (const float4*)(ws + OFF_A  + j * 512 + rg * 32);
        const float4* Cg = (const float4*)(ws + OFF_C  + j * 512 + rg * 32);
        const float4* Wg = (const float4*)(ws + OFF_WE + j * 512 + rg * 32);
        #pragma unroll
        for (int q = 0; q < 8; ++q) {
            const float4 ua = Ag[q];
            pa[q * 4 + 0] = ua.x; pa[q * 4 + 1] = ua.y; pa[q * 4 + 2] = ua.z; pa[q * 4 + 3] = ua.w;
            const float4 uc = Cg[q];
            pc[q * 4 + 0] = uc.x; pc[q * 4 + 1] = uc.y; pc[q * 4 + 2] = uc.z; pc[q * 4 + 3] = uc.w;
            const float4 uw = Wg[q];
            pwe[q * 4 + 0] = uw.x; pwe[q * 4 + 1] = uw.y; pwe[q * 4 + 2] = uw.z; pwe[q * 4 + 3] = uw.w;
        }
    }
    float gl = 0.f, glvl = 0.f, cmt = 0.f, ow = 0.f, ob = 0.f, vown = 0.f, sn = 0.f, sd = 0.f;
    if (owner) {
        gl = gleak[j]; glvl = gl * vleak[j]; cmt = cmv[j] * 6.f;
        if (j < Hh) { ow = outw[j]; ob = outb[j]; }
    }
    float* ring = ws + OFF_RING + batch * 4096;   // [8][512]
    const float* snb = ws + OFF_NUMS + batch * (Ss * Uu);
    const float* sdb = ws + OFF_DENS + batch * (Ss * Uu);
    float* ltc = ws + OFF_LTC;

    unsigned phase = 0;
    const unsigned rxor = (unsigned)((rg & 7) << 2);   // read swizzle for this lane

    for (int step = 0; step < Ss; ++step) {
        if (owner) { sn = snb[step * Uu + j]; sd = sdb[step * Uu + j]; }
        for (int uf = 0; uf < 6; ++uf) {
            // (a) reset ring slot phase+4 (all waves provably >= phase, readers of it done)
            if (owner) {
                __hip_atomic_store(ring + (((phase + 4) & 7) << 9) + j,
                                   __builtin_bit_cast(float, SENT_U),
                                   __ATOMIC_RELAXED, __HIP_MEMORY_SCOPE_AGENT);
            }
            // (b) poll v_{phase-1}: 8 coalesced slots per lane (slot m*64+lane)
            {
                const float* src = ring + (((phase + 7) & 7) << 9);
                float pvv[8];
                unsigned stale = 0xFFu;
                do {
                    #pragma unroll
                    for (int m = 0; m < 8; ++m) {
                        if (stale & (1u << m)) {
                            const float xv = __hip_atomic_load(src + (m << 6) + lane,
                                                               __ATOMIC_RELAXED, __HIP_MEMORY_SCOPE_AGENT);
                            pvv[m] = xv;
                            if (__builtin_bit_cast(unsigned, xv) != SENT_U) stale &= ~(1u << m);
                        }
                    }
                } while (stale);
                // (c) stage into own wave's swizzled LDS tile (no conflicts, no barrier)
                #pragma unroll
                for (int m = 0; m < 8; ++m) {
                    const int s = (m << 6) + lane;
                    vlds[wv][s ^ (((s >> 5) & 7) << 2)] = pvv[m];
                }
            }
            // (d) 32 edge evals: 4 VALU + 2 trans each (|we| via free abs modifier)
            float n0 = 0.f, n1 = 0.f, d0 = 0.f, d1 = 0.f;
            #pragma unroll
            for (int k4 = 0; k4 < 8; ++k4) {
                const int widx = (unsigned)(rg * 32 + k4 * 4) ^ rxor;
                const float4 v4 = *(const float4*)&vlds[wv][widx];
                {
                    const int k = k4 * 4 + 0;
                    const float r = rcpf(1.f + ex2(fmaf(-pa[k], v4.x, pc[k])));
                    n0 = fmaf(pwe[k], r, n0); d0 = fmaf(fabsf(pwe[k]), r, d0);
                }
                {
                    const int k = k4 * 4 + 1;
                    const float r = rcpf(1.f + ex2(fmaf(-pa[k], v4.y, pc[k])));
                    n1 = fmaf(pwe[k], r, n1); d1 = fmaf(fabsf(pwe[k]), r, d1);
                }
                {
                    const int k = k4 * 4 + 2;
                    const float r = rcpf(1.f + ex2(fmaf(-pa[k], v4.z, pc[k])));
                    n0 = fmaf(pwe[k], r, n0); d0 = fmaf(fabsf(pwe[k]), r, d0);
                }
                {
                    const int k = k4 * 4 + 3;
                    const float r = rcpf(1.f + ex2(fmaf(-pa[k], v4.w, pc[k])));
                    n1 = fmaf(pwe[k], r, n1); d1 = fmaf(fabsf(pwe[k]), r, d1);
                }
            }
            // (e) reduce over rg (bits 2..5 of lane), colL kept separate
            float n = n0 + n1, d = d0 + d1;
            n += __shfl_xor(n, 4, 64);  d += __shfl_xor(d, 4, 64);
            n += __shfl_xor(n, 8, 64);  d += __shfl_xor(d, 8, 64);
            n += __shfl_xor(n, 16, 64); d += __shfl_xor(d, 16, 64);
            n += __shfl_xor(n, 32, 64); d += __shfl_xor(d, 32, 64);
            // (f) owner update + fire-and-forget store
            if (owner) {
                const float rn = n + sn, rd = d + sd;
                const float vnew = (fmaf(cmt, vown, glvl) + rn) * rcpf(cmt + gl + rd + 1e-8f);
                vown = vnew;
                __hip_atomic_store(ring + ((phase & 7) << 9) + j, vnew,
                                   __ATOMIC_RELAXED, __HIP_MEMORY_SCOPE_AGENT);
            }
            ++phase;
        }
        if (owner && j < Hh) ltc[(batch * Ss + step) * Hh + j] = fmaf(vown, ow, ob);
    }
    if (owner) dout[524288 + 131072 + batch * Uu + j] = vown;
}

// ---------------- generic fp32 tiled GEMM, K=256. MODE: 0 bias, 1 qkv-permute, 2 +residual, 3 silu ----------------
template <int MODE>
__global__ __launch_bounds__(256) void gemm_kernel(
    const float* __restrict__ A, const float* __restrict__ W,
    const float* __restrict__ bias, const float* __restrict__ R,
    float* __restrict__ C, const int N, const float scale)
{
    __shared__ float As[16][64];
    __shared__ float Bs[16][64];
    const int t = threadIdx.x;
    const int tx = t & 15, ty = t >> 4;
    const int by = blockIdx.x, bx = blockIdx.y;
    float acc[4][4] = {{0.f}};
    constexpr int K = 256;
    for (int k0 = 0; k0 < K; k0 += 16) {
        {
            const int r = t >> 2, c4 = (t & 3) << 2;
            const float4 a4 = *(const float4*)&A[(by * 64 + r) * K + k0 + c4];
            As[c4 + 0][r] = a4.x; As[c4 + 1][r] = a4.y; As[c4 + 2][r] = a4.z; As[c4 + 3][r] = a4.w;
        }
        {
            const int r = t >> 4, c4 = (t & 15) << 2;
            *(float4*)&Bs[r][c4] = *(const float4*)&W[(k0 + r) * N + bx * 64 + c4];
        }
        __syncthreads();
        #pragma unroll
        for (int kk = 0; kk < 16; ++kk) {
            const float4 a4 = *(const float4*)&As[kk][ty << 2];
            const float4 b4 = *(const float4*)&Bs[kk][tx << 2];
            acc[0][0] = fmaf(a4.x, b4.x, acc[0][0]); acc[0][1] = fmaf(a4.x, b4.y, acc[0][1]);
            acc[0][2] = fmaf(a4.x, b4.z, acc[0][2]); acc[0][3] = fmaf(a4.x, b4.w, acc[0][3]);
            acc[1][0] = fmaf(a4.y, b4.x, acc[1][0]); acc[1][1] = fmaf(a4.y, b4.y, acc[1][1]);
            acc[1][2] = fmaf(a4.y, b4.z, acc[1][2]); acc[1][3] = fmaf(a4.y, b4.w, acc[1][3]);
            acc[2][0] = fmaf(a4.z, b4.x, acc[2][0]); acc[2][1] = fmaf(a4.z, b4.y, acc[2][1]);
            acc[2][2] = fmaf(a4.z, b4.z, acc[2][2]); acc[2][3] = fmaf(a4.z, b4.w, acc[2][3]);
            acc[3][0] = fmaf(a4.w, b4.x, acc[3][0]); acc[3][1] = fmaf(a4.w, b4.y, acc[3][1]);
            acc[3][2] = fmaf(a4.w, b4.z, acc[3][2]); acc[3][3] = fmaf(a4.w, b4.w, acc[3][3]);
        }
        __syncthreads();
    }
    const int n0 = bx * 64 + (tx << 2);
    const float4 bv = *(const float4*)&bias[n0];
    #pragma unroll
    for (int i2 = 0; i2 < 4; ++i2) {
        const int m = by * 64 + (ty << 2) + i2;
        float4 o;
        o.x = acc[i2][0] + bv.x; o.y = acc[i2][1] + bv.y;
        o.z = acc[i2][2] + bv.z; o.w = acc[i2][3] + bv.w;
        if (MODE == 1) {
            o.x *= scale; o.y *= scale; o.z *= scale; o.w *= scale;
            const int b = m >> 7, s = m & 127;
            const int h = n0 >> 6, d = n0 & 63;
            *(float4*)&C[((b * 4 + h) * 128 + s) * 64 + d] = o;
        } else if (MODE == 2) {
            const float4 rv = *(const float4*)&R[m * N + n0];
            o.x += rv.x; o.y += rv.y; o.z += rv.z; o.w += rv.w;
            *(float4*)&C[m * N + n0] = o;
        } else if (MODE == 3) {
            o.x = o.x * rcpf(1.f + ex2(-o.x * L2E));
            o.y = o.y * rcpf(1.f + ex2(-o.y * L2E));
            o.z = o.z * rcpf(1.f + ex2(-o.z * L2E));
            o.w = o.w * rcpf(1.f + ex2(-o.w * L2E));
            *(float4*)&C[m * N + n0] = o;
        } else {
            *(float4*)&C[m * N + n0] = o;
        }
    }
}

// ---------------- attention: per (b,h,16-q-rows) block ----------------
__global__ __launch_bounds__(256) void attn_kernel(
    const float* __restrict__ q, const float* __restrict__ k,
    const float* __restrict__ v, float* __restrict__ mem)
{
    __shared__ float KV[128 * 66];
    __shared__ float Qs[16 * 66];
    __shared__ float P[16 * 128];
    const int t = threadIdx.x;
    const int qb = blockIdx.x & 7;
    const int bh = blockIdx.x >> 3;
    const float* qp = q + bh * (128 * 64);
    const float* kp = k + bh * (128 * 64);
    const float* vp = v + bh * (128 * 64);
    {
        const int r = t >> 4, d4 = (t & 15) << 2;
        const float4 x4 = *(const float4*)&qp[(qb * 16 + r) * 64 + d4];
        Qs[r * 66 + d4 + 0] = x4.x; Qs[r * 66 + d4 + 1] = x4.y;
        Qs[r * 66 + d4 + 2] = x4.z; Qs[r * 66 + d4 + 3] = x4.w;
    }
    #pragma unroll
    for (int e = 0; e < 8; ++e) {
        const int id = t + e * 256;
        const int s = id >> 4, d4 = (id & 15) << 2;
        const float4 x4 = *(const float4*)&kp[s * 64 + d4];
        KV[s * 66 + d4 + 0] = x4.x; KV[s * 66 + d4 + 1] = x4.y;
        KV[s * 66 + d4 + 2] = x4.z; KV[s * 66 + d4 + 3] = x4.w;
    }
    __syncthreads();
    const int qi = t >> 4, sc = t & 15;
    float pv[8];
    float mx = -3.4e38f;
    #pragma unroll
    for (int s8 = 0; s8 < 8; ++s8) {
        const int s = s8 * 16 + sc;
        float dot = 0.f;
        #pragma unroll
        for (int d4 = 0; d4 < 16; ++d4) {
            const float4 qv = *(const float4*)&Qs[qi * 66 + d4 * 4];
            const float4 kv = *(const float4*)&KV[s * 66 + d4 * 4];
            dot = fmaf(qv.x, kv.x, dot); dot = fmaf(qv.y, kv.y, dot);
            dot = fmaf(qv.z, kv.z, dot); dot = fmaf(qv.w, kv.w, dot);
        }
        pv[s8] = dot;
        mx = fmaxf(mx, dot);
    }
    #pragma unroll
    for (int off = 1; off < 16; off <<= 1) mx = fmaxf(mx, __shfl_xor(mx, off, 16));
    float sum = 0.f;
    #pragma unroll
    for (int s8 = 0; s8 < 8; ++s8) {
        const int s = s8 * 16 + sc;
        const float p = ex2((pv[s8] - mx) * L2E);
        P[qi * 128 + s] = p;
        sum += p;
    }
    #pragma unroll
    for (int off = 1; off < 16; off <<= 1) sum += __shfl_xor(sum, off, 16);
    const float inv = rcpf(sum);
    __syncthreads();
    #pragma unroll
    for (int e = 0; e < 8; ++e) {
        const int id = t + e * 256;
        const int s = id >> 4, d4 = (id & 15) << 2;
        *(float4*)&KV[s * 64 + d4] = *(const float4*)&vp[s * 64 + d4];
    }
    __syncthreads();
    float4 acc = {0.f, 0.f, 0.f, 0.f};
    for (int s = 0; s < 128; ++s) {
        const float p = P[qi * 128 + s];
        const float4 v4 = *(const float4*)&KV[s * 64 + (sc << 2)];
        acc.x = fmaf(p, v4.x, acc.x); acc.y = fmaf(p, v4.y, acc.y);
        acc.z = fmaf(p, v4.z, acc.z); acc.w = fmaf(p, v4.w, acc.w);
    }
    acc.x *= inv; acc.y *= inv; acc.z *= inv; acc.w *= inv;
    const int b = bh >> 2, h = bh & 3;
    const int m = b * 128 + qb * 16 + qi;
    *(float4*)&mem[m * 256 + h * 64 + (sc << 2)] = acc;
}

extern "C" void kernel_launch(void* const* d_in, const int* in_sizes, int n_in,
                              void* d_out, int out_size, void* d_ws, size_t ws_size,
                              hipStream_t stream)
{
    const float* x     = (const float*)d_in[0];
    const float* inw   = (const float*)d_in[1];
    const float* inb   = (const float*)d_in[2];
    const float* gleak = (const float*)d_in[3];
    const float* vleak = (const float*)d_in[4];
    const float* cm    = (const float*)d_in[5];
    const float* sigma = (const float*)d_in[6];
    const float* mu    = (const float*)d_in[7];
    const float* w     = (const float*)d_in[8];
    const float* erev  = (const float*)d_in[9];
    const float* maskr = (const float*)d_in[10];
    const float* ssig  = (const float*)d_in[11];
    const float* smu   = (const float*)d_in[12];
    const float* sw    = (const float*)d_in[13];
    const float* serev = (const float*)d_in[14];
    const float* smask = (const float*)d_in[15];
    const float* outw  = (const float*)d_in[16];
    const float* outb  = (const float*)d_in[17];
    const float* Wq    = (const float*)d_in[18];
    const float* bq    = (const float*)d_in[19];
    const float* Wk    = (const float*)d_in[20];
    const float* bk    = (const float*)d_in[21];
    const float* Wv    = (const float*)d_in[22];
    const float* bv    = (const float*)d_in[23];
    const float* Wo    = (const float*)d_in[24];
    const float* bo    = (const float*)d_in[25];
    const float* W1    = (const float*)d_in[26];
    const float* b1    = (const float*)d_in[27];
    const float* W2    = (const float*)d_in[28];
    const float* b2    = (const float*)d_in[29];

    float* ws  = (float*)d_ws;
    float* out = (float*)d_out;

    prep_kernel<<<1024, 256, 0, stream>>>(sigma, mu, w, erev, maskr, ws);
    sensory_kernel<<<1024, 256, 0, stream>>>(x, inw, inb, ssig, smu, sw, serev, smask, ws);
    scan_kernel<<<512, 256, 0, stream>>>(gleak, vleak, cm, outw, outb, ws, out);

    dim3 gA(32, 4);
    gemm_kernel<1><<<gA, 256, 0, stream>>>(ws + OFF_LTC, Wq, bq, nullptr, ws + OFF_Q, 256, 0.125f);
    gemm_kernel<1><<<gA, 256, 0, stream>>>(ws + OFF_LTC, Wk, bk, nullptr, ws + OFF_K, 256, 1.f);
    gemm_kernel<1><<<gA, 256, 0, stream>>>(ws + OFF_LTC, Wv, bv, nullptr, ws + OFF_V, 256, 1.f);
    attn_kernel<<<512, 256, 0, stream>>>(ws + OFF_Q, ws + OFF_K, ws + OFF_V, ws + OFF_MEM);
    gemm_kernel<2><<<gA, 256, 0, stream>>>(ws + OFF_MEM, Wo, bo, ws + OFF_LTC, out, 256, 1.f);
    gemm_kernel<3><<<gA, 256, 0, stream>>>(out, W1, b1, nullptr, ws + OFF_HID, 256, 1.f);
    dim3 gB(32, 1);
    gemm_kernel<0><<<gB, 256, 0, stream>>>(ws + OFF_HID, W2, b2, nullptr, out + 524288, 64, 1.f);
}

// Round 5
// 2341.010 us; speedup vs baseline: 1.4097x; 1.4097x over previous
//
#include <hip/hip_runtime.h>
#include <hip/hip_fp16.h>

#define L2E 1.4426950408889634f

// Problem dims
constexpr int Bb = 16, Ss = 128, Ii = 576, Uu = 512, Hh = 256;

// ws offsets (in 4-byte slots) — scan-phase layout
constexpr int OFF_A    = 0;        // 262144 f32  a  = sigma*log2e,      [j][i]
constexpr int OFF_C    = 262144;   // 262144 f32  c  = sigma*mu*log2e,   [j][i]
constexpr int OFF_WE   = 524288;   // 262144 f32  we = w*mask*erev,      [j][i]
constexpr int OFF_NUMS = 786432;   // 1048576 f32 sensory numerators (B*S, U)
constexpr int OFF_DENS = 1835008;  // 1048576 f32
constexpr int OFF_RING = 2883584;  // 65536 f32   [batch][8][512] v-exchange ring
constexpr int OFF_LTC  = 2949120;  // 524288 f32  ltc_out (B,S,H)
// post-scan overlays (params + NUMS/DENS dead after scan)
constexpr int OFF_Q    = 0;
constexpr int OFF_K    = 524288;
constexpr int OFF_V    = 1048576;
constexpr int OFF_MEM  = 1572864;
constexpr int OFF_HID  = 2097152;

constexpr unsigned SENT_U = 0x7FBADBADu;  // NaN-payload sentinel, unreachable by the LTC math

__device__ __forceinline__ float ex2(float x) { return __builtin_amdgcn_exp2f(x); }
__device__ __forceinline__ float rcpf(float x) { return __builtin_amdgcn_rcpf(x); }

// ---------------- param prep: f32 derived edge params, transposed to [j][i] ----------------
__global__ __launch_bounds__(256) void prep_kernel(
    const float* __restrict__ sigma, const float* __restrict__ mu,
    const float* __restrict__ w, const float* __restrict__ erev,
    const float* __restrict__ mask, float* __restrict__ ws)
{
    const int g = blockIdx.x * 256 + threadIdx.x;   // [0, 262144)
    // ring init: [batch][8][512]; slot 7 = h0 zeros, others sentinel
    if (g < 16 * 8 * 512) {
        const int r = (g >> 9) & 7;
        ws[OFF_RING + g] = (r == 7) ? 0.0f : __builtin_bit_cast(float, SENT_U);
    }
    const int jj = g & 511, i = g >> 9;             // coalesced source reads
    const int idx = i * 512 + jj;
    const float sg = sigma[idx], m = mu[idx];
    const float wm = w[idx] * mask[idx];
    const int tr = jj * 512 + i;                    // transposed (scatter) writes
    ws[OFF_A + tr]  = sg * L2E;
    ws[OFF_C + tr]  = sg * m * L2E;
    ws[OFF_WE + tr] = wm * erev[idx];
}

// ---------------- sensory precompute: w_num_s / w_den_s for all (b,t) ----------------
__global__ __launch_bounds__(256) void sensory_kernel(
    const float* __restrict__ x, const float* __restrict__ inw, const float* __restrict__ inb,
    const float* __restrict__ ssig, const float* __restrict__ smu,
    const float* __restrict__ sw, const float* __restrict__ serev,
    const float* __restrict__ smask, float* __restrict__ ws)
{
    __shared__ float inp[16 * 576];
    __shared__ float part[4096];               // [4][64][8][2]
    const int t = threadIdx.x;
    const int jb = blockIdx.x & 7, pb = blockIdx.x >> 3;
    #pragma unroll
    for (int e = 0; e < 9; ++e) {
        const int id = t + e * 256;            // [0,2304)
        const int off = id * 4;
        const int bs = off / 576, ii = off % 576;
        const float4 xv = *(const float4*)&x[(pb * 16 + bs) * 576 + ii];
        const float4 wv = *(const float4*)&inw[ii];
        const float4 bv = *(const float4*)&inb[ii];
        inp[off + 0] = fmaf(xv.x, wv.x, bv.x);
        inp[off + 1] = fmaf(xv.y, wv.y, bv.y);
        inp[off + 2] = fmaf(xv.z, wv.z, bv.z);
        inp[off + 3] = fmaf(xv.w, wv.w, bv.w);
    }
    __syncthreads();
    const int j = t & 63, c = t >> 6;
    const int jg = jb * 64 + j;
    float num[16], den[16];
    #pragma unroll
    for (int bs = 0; bs < 16; ++bs) { num[bs] = 0.f; den[bs] = 0.f; }
    for (int ii = c * 144; ii < (c + 1) * 144; ++ii) {
        const int pidx = ii * 512 + jg;
        const float sg = ssig[pidx], m = smu[pidx];
        const float wm = sw[pidx] * smask[pidx];
        const float we = wm * serev[pidx];
        const float a = sg * L2E, cc = sg * m * L2E;
        #pragma unroll
        for (int bs = 0; bs < 16; ++bs) {
            const float vv = inp[bs * 576 + ii];
            const float r = rcpf(1.f + ex2(fmaf(-a, vv, cc)));
            num[bs] = fmaf(we, r, num[bs]);
            den[bs] = fmaf(wm, r, den[bs]);
        }
    }
    #pragma unroll
    for (int pass = 0; pass < 2; ++pass) {
        __syncthreads();
        #pragma unroll
        for (int bs = 0; bs < 8; ++bs) {
            part[((c * 64 + j) * 8 + bs) * 2 + 0] = num[pass * 8 + bs];
            part[((c * 64 + j) * 8 + bs) * 2 + 1] = den[pass * 8 + bs];
        }
        __syncthreads();
        #pragma unroll
        for (int qd = 0; qd < 4; ++qd) {
            const int vid = t * 4 + qd;        // [0,1024)
            const int jj2 = vid >> 4, bs = (vid >> 1) & 7, which = vid & 1;
            const float acc =
                part[((0 * 64 + jj2) * 8 + bs) * 2 + which] + part[((1 * 64 + jj2) * 8 + bs) * 2 + which] +
                part[((2 * 64 + jj2) * 8 + bs) * 2 + which] + part[((3 * 64 + jj2) * 8 + bs) * 2 + which];
            const int p = pb * 16 + pass * 8 + bs;
            ws[(which ? OFF_DENS : OFF_NUMS) + p * 512 + jb * 64 + jj2] = acc;
        }
    }
}

// ---------------- persistent LTC scan v5: f32 reg params + WG-cooperative poll ----------------
// 512 WGs = 16 batches x 32 slices. Wave owns 4 columns (lane = rg*4+colL, rg owns rows
// rg*32..+31). Sync per phase: each THREAD polls exactly 2 ring slots (t, t+256) -> 512
// agent-scope loads per WG total (minimal fabric pressure; round-4's per-wave polling at 4x
// traffic regressed 1.6x) -> stage into double-buffered swizzled LDS tile -> ONE barrier ->
// 32 edge evals/lane from LDS -> 4x shfl_xor reduce -> owner lanes update + fire-and-forget
// store. Sentinel-ring (8 slots, reset at distance 4; skew <= ~1 phase since any wave at
// phase p has observed all owners' p-1 stores). Same-address store-store (reset then vnew,
// distance 4) is same-thread -> coherence-ordered.
__global__ __launch_bounds__(256, 2) void scan_kernel(
    const float* __restrict__ gleak, const float* __restrict__ vleak,
    const float* __restrict__ cmv,
    const float* __restrict__ outw, const float* __restrict__ outb,
    float* __restrict__ ws, float* __restrict__ dout)
{
    __shared__ float vlds[2][512];     // 4 KB, double-buffered, XOR-swizzled (0 conflicts, r4-verified)

    const int t = threadIdx.x;
    const int wg = blockIdx.x;
    const int batch = wg & 15;
    const int slice = wg >> 4;
    const int wv = t >> 6;
    const int lane = t & 63;
    const int rg = lane >> 2;          // 0..15 -> rows rg*32..+31
    const int colL = lane & 3;
    const int j = slice * 16 + wv * 4 + colL;
    const bool owner = (lane < 4);     // rg == 0

    // one-time: f32 edge params into registers (96 VGPRs)
    float pa[32], pc[32], pwe[32];
    {
        const float4* Ag = (const float4*)(ws + OFF_A  + j * 512 + rg * 32);
        const float4* Cg = (const float4*)(ws + OFF_C  + j * 512 + rg * 32);
        const float4* Wg = (const float4*)(ws + OFF_WE + j * 512 + rg * 32);
        #pragma unroll
        for (int q = 0; q < 8; ++q) {
            const float4 ua = Ag[q];
            pa[q * 4 + 0] = ua.x; pa[q * 4 + 1] = ua.y; pa[q * 4 + 2] = ua.z; pa[q * 4 + 3] = ua.w;
            const float4 uc = Cg[q];
            pc[q * 4 + 0] = uc.x; pc[q * 4 + 1] = uc.y; pc[q * 4 + 2] = uc.z; pc[q * 4 + 3] = uc.w;
            const float4 uw = Wg[q];
            pwe[q * 4 + 0] = uw.x; pwe[q * 4 + 1] = uw.y; pwe[q * 4 + 2] = uw.z; pwe[q * 4 + 3] = uw.w;
        }
    }
    float gl = 0.f, glvl = 0.f, cmt = 0.f, ow = 0.f, ob = 0.f, vown = 0.f, sn = 0.f, sd = 0.f;
    if (owner) {
        gl = gleak[j]; glvl = gl * vleak[j]; cmt = cmv[j] * 6.f;
        if (j < Hh) { ow = outw[j]; ob = outb[j]; }
    }
    float* ring = ws + OFF_RING + batch * 4096;   // [8][512]
    const float* snb = ws + OFF_NUMS + batch * (Ss * Uu);
    const float* sdb = ws + OFF_DENS + batch * (Ss * Uu);
    float* ltc = ws + OFF_LTC;

    unsigned phase = 0;
    int buf = 0;
    const int swA = t ^ (((t >> 5) & 7) << 2);            // swizzled LDS index for slot t
    const int swB = (t + 256) ^ ((((t + 256) >> 5) & 7) << 2);
    const unsigned rxor = (unsigned)((rg & 7) << 2);      // read swizzle for this lane

    for (int step = 0; step < Ss; ++step) {
        if (owner) { sn = snb[step * Uu + j]; sd = sdb[step * Uu + j]; }
        for (int uf = 0; uf < 6; ++uf) {
            // (a) WG-cooperative poll of v_{phase-1}: 2 slots per thread
            {
                const float* src = ring + (((phase + 7) & 7) << 9);
                float va = 0.f, vc = 0.f;
                unsigned ua = SENT_U, uc = SENT_U;
                do {
                    if (ua == SENT_U) {
                        va = __hip_atomic_load(src + t, __ATOMIC_RELAXED, __HIP_MEMORY_SCOPE_AGENT);
                        ua = __builtin_bit_cast(unsigned, va);
                    }
                    if (uc == SENT_U) {
                        vc = __hip_atomic_load(src + t + 256, __ATOMIC_RELAXED, __HIP_MEMORY_SCOPE_AGENT);
                        uc = __builtin_bit_cast(unsigned, vc);
                    }
                } while (ua == SENT_U || uc == SENT_U);
                vlds[buf][swA] = va; vlds[buf][swB] = vc;
            }
            // (b) reset ring slot phase+4 (after poll so poll loads lead the memory pipe)
            if (owner) {
                __hip_atomic_store(ring + (((phase + 4) & 7) << 9) + j,
                                   __builtin_bit_cast(float, SENT_U),
                                   __ATOMIC_RELAXED, __HIP_MEMORY_SCOPE_AGENT);
            }
            __syncthreads();   // the ONLY barrier per phase (dbuf covers WAR across phases)

            // (c) 32 edge evals: 4 VALU + 2 trans each
            float n0 = 0.f, n1 = 0.f, d0 = 0.f, d1 = 0.f;
            const float* vb = vlds[buf];
            #pragma unroll
            for (int k4 = 0; k4 < 8; ++k4) {
                const int widx = (unsigned)(rg * 32 + k4 * 4) ^ rxor;
                const float4 v4 = *(const float4*)&vb[widx];
                {
                    const int k = k4 * 4 + 0;
                    const float r = rcpf(1.f + ex2(fmaf(-pa[k], v4.x, pc[k])));
                    n0 = fmaf(pwe[k], r, n0); d0 = fmaf(fabsf(pwe[k]), r, d0);
                }
                {
                    const int k = k4 * 4 + 1;
                    const float r = rcpf(1.f + ex2(fmaf(-pa[k], v4.y, pc[k])));
                    n1 = fmaf(pwe[k], r, n1); d1 = fmaf(fabsf(pwe[k]), r, d1);
                }
                {
                    const int k = k4 * 4 + 2;
                    const float r = rcpf(1.f + ex2(fmaf(-pa[k], v4.z, pc[k])));
                    n0 = fmaf(pwe[k], r, n0); d0 = fmaf(fabsf(pwe[k]), r, d0);
                }
                {
                    const int k = k4 * 4 + 3;
                    const float r = rcpf(1.f + ex2(fmaf(-pa[k], v4.w, pc[k])));
                    n1 = fmaf(pwe[k], r, n1); d1 = fmaf(fabsf(pwe[k]), r, d1);
                }
            }
            // (d) reduce over rg (lane bits 2..5); colL kept separate
            float n = n0 + n1, d = d0 + d1;
            n += __shfl_xor(n, 4, 64);  d += __shfl_xor(d, 4, 64);
            n += __shfl_xor(n, 8, 64);  d += __shfl_xor(d, 8, 64);
            n += __shfl_xor(n, 16, 64); d += __shfl_xor(d, 16, 64);
            n += __shfl_xor(n, 32, 64); d += __shfl_xor(d, 32, 64);
            // (e) owner update + fire-and-forget store
            if (owner) {
                const float rn = n + sn, rd = d + sd;
                const float vnew = (fmaf(cmt, vown, glvl) + rn) * rcpf(cmt + gl + rd + 1e-8f);
                vown = vnew;
                __hip_atomic_store(ring + ((phase & 7) << 9) + j, vnew,
                                   __ATOMIC_RELAXED, __HIP_MEMORY_SCOPE_AGENT);
            }
            ++phase; buf ^= 1;
        }
        if (owner && j < Hh) ltc[(batch * Ss + step) * Hh + j] = fmaf(vown, ow, ob);
    }
    if (owner) dout[524288 + 131072 + batch * Uu + j] = vown;
}

// ---------------- generic fp32 tiled GEMM, K=256. MODE: 0 bias, 1 qkv-permute, 2 +residual, 3 silu ----------------
template <int MODE>
__global__ __launch_bounds__(256) void gemm_kernel(
    const float* __restrict__ A, const float* __restrict__ W,
    const float* __restrict__ bias, const float* __restrict__ R,
    float* __restrict__ C, const int N, const float scale)
{
    __shared__ float As[16][64];
    __shared__ float Bs[16][64];
    const int t = threadIdx.x;
    const int tx = t & 15, ty = t >> 4;
    const int by = blockIdx.x, bx = blockIdx.y;
    float acc[4][4] = {{0.f}};
    constexpr int K = 256;
    for (int k0 = 0; k0 < K; k0 += 16) {
        {
            const int r = t >> 2, c4 = (t & 3) << 2;
            const float4 a4 = *(const float4*)&A[(by * 64 + r) * K + k0 + c4];
            As[c4 + 0][r] = a4.x; As[c4 + 1][r] = a4.y; As[c4 + 2][r] = a4.z; As[c4 + 3][r] = a4.w;
        }
        {
            const int r = t >> 4, c4 = (t & 15) << 2;
            *(float4*)&Bs[r][c4] = *(const float4*)&W[(k0 + r) * N + bx * 64 + c4];
        }
        __syncthreads();
        #pragma unroll
        for (int kk = 0; kk < 16; ++kk) {
            const float4 a4 = *(const float4*)&As[kk][ty << 2];
            const float4 b4 = *(const float4*)&Bs[kk][tx << 2];
            acc[0][0] = fmaf(a4.x, b4.x, acc[0][0]); acc[0][1] = fmaf(a4.x, b4.y, acc[0][1]);
            acc[0][2] = fmaf(a4.x, b4.z, acc[0][2]); acc[0][3] = fmaf(a4.x, b4.w, acc[0][3]);
            acc[1][0] = fmaf(a4.y, b4.x, acc[1][0]); acc[1][1] = fmaf(a4.y, b4.y, acc[1][1]);
            acc[1][2] = fmaf(a4.y, b4.z, acc[1][2]); acc[1][3] = fmaf(a4.y, b4.w, acc[1][3]);
            acc[2][0] = fmaf(a4.z, b4.x, acc[2][0]); acc[2][1] = fmaf(a4.z, b4.y, acc[2][1]);
            acc[2][2] = fmaf(a4.z, b4.z, acc[2][2]); acc[2][3] = fmaf(a4.z, b4.w, acc[2][3]);
            acc[3][0] = fmaf(a4.w, b4.x, acc[3][0]); acc[3][1] = fmaf(a4.w, b4.y, acc[3][1]);
            acc[3][2] = fmaf(a4.w, b4.z, acc[3][2]); acc[3][3] = fmaf(a4.w, b4.w, acc[3][3]);
        }
        __syncthreads();
    }
    const int n0 = bx * 64 + (tx << 2);
    const float4 bv = *(const float4*)&bias[n0];
    #pragma unroll
    for (int i2 = 0; i2 < 4; ++i2) {
        const int m = by * 64 + (ty << 2) + i2;
        float4 o;
        o.x = acc[i2][0] + bv.x; o.y = acc[i2][1] + bv.y;
        o.z = acc[i2][2] + bv.z; o.w = acc[i2][3] + bv.w;
        if (MODE == 1) {
            o.x *= scale; o.y *= scale; o.z *= scale; o.w *= scale;
            const int b = m >> 7, s = m & 127;
            const int h = n0 >> 6, d = n0 & 63;
            *(float4*)&C[((b * 4 + h) * 128 + s) * 64 + d] = o;
        } else if (MODE == 2) {
            const float4 rv = *(const float4*)&R[m * N + n0];
            o.x += rv.x; o.y += rv.y; o.z += rv.z; o.w += rv.w;
            *(float4*)&C[m * N + n0] = o;
        } else if (MODE == 3) {
            o.x = o.x * rcpf(1.f + ex2(-o.x * L2E));
            o.y = o.y * rcpf(1.f + ex2(-o.y * L2E));
            o.z = o.z * rcpf(1.f + ex2(-o.z * L2E));
            o.w = o.w * rcpf(1.f + ex2(-o.w * L2E));
            *(float4*)&C[m * N + n0] = o;
        } else {
            *(float4*)&C[m * N + n0] = o;
        }
    }
}

// ---------------- attention: per (b,h,16-q-rows) block ----------------
__global__ __launch_bounds__(256) void attn_kernel(
    const float* __restrict__ q, const float* __restrict__ k,
    const float* __restrict__ v, float* __restrict__ mem)
{
    __shared__ float KV[128 * 66];
    __shared__ float Qs[16 * 66];
    __shared__ float P[16 * 128];
    const int t = threadIdx.x;
    const int qb = blockIdx.x & 7;
    const int bh = blockIdx.x >> 3;
    const float* qp = q + bh * (128 * 64);
    const float* kp = k + bh * (128 * 64);
    const float* vp = v + bh * (128 * 64);
    {
        const int r = t >> 4, d4 = (t & 15) << 2;
        const float4 x4 = *(const float4*)&qp[(qb * 16 + r) * 64 + d4];
        Qs[r * 66 + d4 + 0] = x4.x; Qs[r * 66 + d4 + 1] = x4.y;
        Qs[r * 66 + d4 + 2] = x4.z; Qs[r * 66 + d4 + 3] = x4.w;
    }
    #pragma unroll
    for (int e = 0; e < 8; ++e) {
        const int id = t + e * 256;
        const int s = id >> 4, d4 = (id & 15) << 2;
        const float4 x4 = *(const float4*)&kp[s * 64 + d4];
        KV[s * 66 + d4 + 0] = x4.x; KV[s * 66 + d4 + 1] = x4.y;
        KV[s * 66 + d4 + 2] = x4.z; KV[s * 66 + d4 + 3] = x4.w;
    }
    __syncthreads();
    const int qi = t >> 4, sc = t & 15;
    float pv[8];
    float mx = -3.4e38f;
    #pragma unroll
    for (int s8 = 0; s8 < 8; ++s8) {
        const int s = s8 * 16 + sc;
        float dot = 0.f;
        #pragma unroll
        for (int d4 = 0; d4 < 16; ++d4) {
            const float4 qv = *(const float4*)&Qs[qi * 66 + d4 * 4];
            const float4 kv = *(const float4*)&KV[s * 66 + d4 * 4];
            dot = fmaf(qv.x, kv.x, dot); dot = fmaf(qv.y, kv.y, dot);
            dot = fmaf(qv.z, kv.z, dot); dot = fmaf(qv.w, kv.w, dot);
        }
        pv[s8] = dot;
        mx = fmaxf(mx, dot);
    }
    #pragma unroll
    for (int off = 1; off < 16; off <<= 1) mx = fmaxf(mx, __shfl_xor(mx, off, 16));
    float sum = 0.f;
    #pragma unroll
    for (int s8 = 0; s8 < 8; ++s8) {
        const int s = s8 * 16 + sc;
        const float p = ex2((pv[s8] - mx) * L2E);
        P[qi * 128 + s] = p;
        sum += p;
    }
    #pragma unroll
    for (int off = 1; off < 16; off <<= 1) sum += __shfl_xor(sum, off, 16);
    const float inv = rcpf(sum);
    __syncthreads();
    #pragma unroll
    for (int e = 0; e < 8; ++e) {
        const int id = t + e * 256;
        const int s = id >> 4, d4 = (id & 15) << 2;
        *(float4*)&KV[s * 64 + d4] = *(const float4*)&vp[s * 64 + d4];
    }
    __syncthreads();
    float4 acc = {0.f, 0.f, 0.f, 0.f};
    for (int s = 0; s < 128; ++s) {
        const float p = P[qi * 128 + s];
        const float4 v4 = *(const float4*)&KV[s * 64 + (sc << 2)];
        acc.x = fmaf(p, v4.x, acc.x); acc.y = fmaf(p, v4.y, acc.y);
        acc.z = fmaf(p, v4.z, acc.z); acc.w = fmaf(p, v4.w, acc.w);
    }
    acc.x *= inv; acc.y *= inv; acc.z *= inv; acc.w *= inv;
    const int b = bh >> 2, h = bh & 3;
    const int m = b * 128 + qb * 16 + qi;
    *(float4*)&mem[m * 256 + h * 64 + (sc << 2)] = acc;
}

extern "C" void kernel_launch(void* const* d_in, const int* in_sizes, int n_in,
                              void* d_out, int out_size, void* d_ws, size_t ws_size,
                              hipStream_t stream)
{
    const float* x     = (const float*)d_in[0];
    const float* inw   = (const float*)d_in[1];
    const float* inb   = (const float*)d_in[2];
    const float* gleak = (const float*)d_in[3];
    const float* vleak = (const float*)d_in[4];
    const float* cm    = (const float*)d_in[5];
    const float* sigma = (const float*)d_in[6];
    const float* mu    = (const float*)d_in[7];
    const float* w     = (const float*)d_in[8];
    const float* erev  = (const float*)d_in[9];
    const float* maskr = (const float*)d_in[10];
    const float* ssig  = (const float*)d_in[11];
    const float* smu   = (const float*)d_in[12];
    const float* sw    = (const float*)d_in[13];
    const float* serev = (const float*)d_in[14];
    const float* smask = (const float*)d_in[15];
    const float* outw  = (const float*)d_in[16];
    const float* outb  = (const float*)d_in[17];
    const float* Wq    = (const float*)d_in[18];
    const float* bq    = (const float*)d_in[19];
    const float* Wk    = (const float*)d_in[20];
    const float* bk    = (const float*)d_in[21];
    const float* Wv    = (const float*)d_in[22];
    const float* bv    = (const float*)d_in[23];
    const float* Wo    = (const float*)d_in[24];
    const float* bo    = (const float*)d_in[25];
    const float* W1    = (const float*)d_in[26];
    const float* b1    = (const float*)d_in[27];
    const float* W2    = (const float*)d_in[28];
    const float* b2    = (const float*)d_in[29];

    float* ws  = (float*)d_ws;
    float* out = (float*)d_out;

    prep_kernel<<<1024, 256, 0, stream>>>(sigma, mu, w, erev, maskr, ws);
    sensory_kernel<<<1024, 256, 0, stream>>>(x, inw, inb, ssig, smu, sw, serev, smask, ws);
    scan_kernel<<<512, 256, 0, stream>>>(gleak, vleak, cm, outw, outb, ws, out);

    dim3 gA(32, 4);
    gemm_kernel<1><<<gA, 256, 0, stream>>>(ws + OFF_LTC, Wq, bq, nullptr, ws + OFF_Q, 256, 0.125f);
    gemm_kernel<1><<<gA, 256, 0, stream>>>(ws + OFF_LTC, Wk, bk, nullptr, ws + OFF_K, 256, 1.f);
    gemm_kernel<1><<<gA, 256, 0, stream>>>(ws + OFF_LTC, Wv, bv, nullptr, ws + OFF_V, 256, 1.f);
    attn_kernel<<<512, 256, 0, stream>>>(ws + OFF_Q, ws + OFF_K, ws + OFF_V, ws + OFF_MEM);
    gemm_kernel<2><<<gA, 256, 0, stream>>>(ws + OFF_MEM, Wo, bo, ws + OFF_LTC, out, 256, 1.f);
    gemm_kernel<3><<<gA, 256, 0, stream>>>(out, W1, b1, nullptr, ws + OFF_HID, 256, 1.f);
    dim3 gB(32, 1);
    gemm_kernel<0><<<gB, 256, 0, stream>>>(ws + OFF_HID, W2, b2, nullptr, out + 524288, 64, 1.f);
}